// Round 9
// baseline (153.619 us; speedup 1.0000x reference)
//
#include <hip/hip_runtime.h>
#include <hip/hip_bf16.h>

#define T_SEQ 2048
#define E_DIM 1024
#define HSZ   64
#define NBAT  4
#define QB    64   // q-rows per attention block
#define NQT   32   // T_SEQ / QB

typedef __attribute__((ext_vector_type(8))) short short8;
typedef __attribute__((ext_vector_type(4))) float f32x4;

__device__ inline short f2bf(float f) {   // fp32 -> bf16 RNE
  union { float f; unsigned u; } v; v.f = f;
  unsigned r = v.u + 0x7FFFu + ((v.u >> 16) & 1u);
  return (short)(r >> 16);
}

// ---------------------------------------------------------------------------
// Kernel 1 (fused prep):
//   idx < 65536 : Wpb[f][j] = bf16(sum_h Wp[h*64+j][f])   (proj B-frags)
//   else        : Wt[kt][n][kk] = bf16(Wsel[kt*64+kk][n&63])  (qkv B-frags)
// ---------------------------------------------------------------------------
__global__ __launch_bounds__(256) void prep_kernel(const float* __restrict__ Wp,
    const float* __restrict__ Wq, const float* __restrict__ Wk,
    const float* __restrict__ Wv, short* __restrict__ Wpb,
    short* __restrict__ Wt) {
  int idx = blockIdx.x * 256 + threadIdx.x;   // 0..262143
  if (idx < 65536) {
    int f = idx & (E_DIM - 1);
    int j = idx >> 10;
    float s = 0.f;
#pragma unroll
    for (int h = 0; h < 16; ++h) s += Wp[(size_t)(h * HSZ + j) * E_DIM + f];
    Wpb[(size_t)f * HSZ + j] = f2bf(s);
  } else {
    int id2 = idx - 65536;                    // 0..196607
    int kk = id2 & 63;
    int tmp = id2 >> 6;
    int kt = tmp / 192;
    int n = tmp - kt * 192;
    const float* W = (n < 64) ? Wq : (n < 128) ? Wk : Wv;
    Wt[id2] = f2bf(W[(size_t)(kt * 64 + kk) * HSZ + (n & 63)]);
  }
}

// ---------------------------------------------------------------------------
// Kernel 2: fused QKV, bf16 MFMA.  C[8192 x 192] = X @ [Wq|Wk|Wv].
// M-tile 32 -> 256 blocks; warp: m-half = (w&1)*16, n-group = (w>>1)*6 tiles.
// Outputs bf16: Q,K row-major [b*t][hs]; V transposed [b][hd][t].
// ---------------------------------------------------------------------------
__global__ __launch_bounds__(256) void qkv_mfma(const float* __restrict__ X,
    const short* __restrict__ Wt, short* __restrict__ Qo,
    short* __restrict__ Ko, short* __restrict__ Vt) {
  __shared__ short Xs[32 * 64];    // [m][k] swizzled
  __shared__ short Ws[192 * 64];   // [n][k] swizzled

  const int tid = threadIdx.x;
  const int m0 = blockIdx.x * 32;
  const int lane = tid & 63, w = tid >> 6;
  const int l15 = lane & 15, l4 = lane >> 4;
  const int mh = (w & 1) * 16;     // m-half base within tile
  const int ng = (w >> 1) * 6;     // first n-tile of this warp (6 tiles)

  f32x4 acc[6];
#pragma unroll
  for (int i = 0; i < 6; ++i) acc[i] = (f32x4)0.f;

  for (int kt = 0; kt < 16; ++kt) {
    const int k0 = kt * 64;
    {   // stage X tile: 32 rows x 8 chunks = exactly 1 chunk/thread
      int r = tid >> 3, c = tid & 7;
      const float* s = &X[(size_t)(m0 + r) * E_DIM + k0 + c * 8];
      float4 a = *(const float4*)s, d = *(const float4*)(s + 4);
      short8 f;
      f[0] = f2bf(a.x); f[1] = f2bf(a.y); f[2] = f2bf(a.z); f[3] = f2bf(a.w);
      f[4] = f2bf(d.x); f[5] = f2bf(d.y); f[6] = f2bf(d.z); f[7] = f2bf(d.w);
      *(short8*)&Xs[r * 64 + ((c ^ (r & 7)) * 8)] = f;
    }
    {   // stage W panel: 192 rows x 8 chunks = 1536 chunks, 6/thread
      const short* wsrc = Wt + (size_t)kt * 12288;
#pragma unroll
      for (int i = 0; i < 6; ++i) {
        int ci = tid + i * 256;
        int r = ci >> 3, c = ci & 7;
        short8 f = *(const short8*)&wsrc[ci * 8];
        *(short8*)&Ws[r * 64 + ((c ^ (r & 7)) * 8)] = f;
      }
    }
    __syncthreads();
#pragma unroll
    for (int ks = 0; ks < 2; ++ks) {
      const int ar = mh + l15;
      short8 af = *(short8*)&Xs[ar * 64 + (((ks * 4 + l4) ^ (ar & 7)) * 8)];
#pragma unroll
      for (int i = 0; i < 6; ++i) {
        int n = (ng + i) * 16 + l15;
        short8 bf = *(short8*)&Ws[n * 64 + (((ks * 4 + l4) ^ (n & 7)) * 8)];
        acc[i] = __builtin_amdgcn_mfma_f32_16x16x32_bf16(af, bf, acc[i], 0, 0, 0);
      }
    }
    __syncthreads();
  }

  // epilogue: C/D layout col=l15, row=l4*4+reg
  const int b = m0 >> 11, t = m0 & 2047;
#pragma unroll
  for (int i = 0; i < 6; ++i) {
    const int nb = ng + i;                // 0..11
    const int col = (nb & 3) * 16 + l15;  // 0..63 within Q/K/V
    const int sel = nb >> 2;
#pragma unroll
    for (int reg = 0; reg < 4; ++reg) {
      const int row = mh + l4 * 4 + reg;  // 0..31
      short v = f2bf(acc[i][reg]);
      if (sel == 0)      Qo[(size_t)(m0 + row) * HSZ + col] = v;
      else if (sel == 1) Ko[(size_t)(m0 + row) * HSZ + col] = v;
      else               Vt[((size_t)b * HSZ + col) * T_SEQ + t + row] = v;
    }
  }
}

// ---------------------------------------------------------------------------
// Kernel 3: split-K causal flash attention partials, bf16 MFMA.
// qt reversed (longest blocks dispatch first).  T14 async-stage double-buffer.
// ---------------------------------------------------------------------------
__global__ __launch_bounds__(256) void attn_part(const short* __restrict__ Q,
    const short* __restrict__ K, const short* __restrict__ Vt,
    float* __restrict__ Opart, float* __restrict__ mpart,
    float* __restrict__ lpart, int splits) {
  const int qt = NQT - 1 - blockIdx.x;   // longest first
  const int sp = blockIdx.y;
  const int b  = blockIdx.z;
  const int ntile = qt + 1;
  const int t0 = (sp * ntile) / splits;
  const int t1 = ((sp + 1) * ntile) / splits;
  const int q0 = qt * QB;
  const int pidx = (b * NQT + qt) * splits + sp;
  float* Op = Opart + (size_t)pidx * QB * HSZ;
  float* mp = mpart + (size_t)pidx * QB;
  float* lp = lpart + (size_t)pidx * QB;
  const int tid = threadIdx.x;

  if (t0 >= t1) {
    if (tid < QB) { mp[tid] = -1e30f; lp[tid] = 0.f; }
    return;
  }

  const short* Qb  = Q  + (size_t)b * T_SEQ * HSZ;
  const short* Kb  = K  + (size_t)b * T_SEQ * HSZ;
  const short* Vtb = Vt + (size_t)b * HSZ * T_SEQ;

  __shared__ short Ks[2][64 * 64];
  __shared__ short Vs[2][64 * 64];
  __shared__ short Ps[4][16 * 64];

  const int lane = tid & 63;
  const int w    = tid >> 6;
  const int l15  = lane & 15;
  const int l4   = lane >> 4;

  const int r0s = tid >> 3,          c0s = tid & 7;
  const int r1s = (tid + 256) >> 3,  c1s = tid & 7;

  short8 kr0, kr1, vr0, vr1;
#define LOADT(kt_) do { \
    const int kv0_ = (kt_) * 64; \
    kr0 = *(const short8*)&Kb[(size_t)(kv0_ + r0s) * HSZ + c0s * 8]; \
    kr1 = *(const short8*)&Kb[(size_t)(kv0_ + r1s) * HSZ + c1s * 8]; \
    vr0 = *(const short8*)&Vtb[(size_t)r0s * T_SEQ + kv0_ + c0s * 8]; \
    vr1 = *(const short8*)&Vtb[(size_t)r1s * T_SEQ + kv0_ + c1s * 8]; \
  } while (0)
#define WRITET(buf_) do { \
    *(short8*)&Ks[buf_][r0s * 64 + ((c0s ^ (r0s & 7)) * 8)] = kr0; \
    *(short8*)&Ks[buf_][r1s * 64 + ((c1s ^ (r1s & 7)) * 8)] = kr1; \
    *(short8*)&Vs[buf_][r0s * 64 + ((c0s ^ (r0s & 7)) * 8)] = vr0; \
    *(short8*)&Vs[buf_][r1s * 64 + ((c1s ^ (r1s & 7)) * 8)] = vr1; \
  } while (0)

  short8 qf[2];
#pragma unroll
  for (int ks = 0; ks < 2; ++ks)
    qf[ks] = *(const short8*)&Qb[(size_t)(q0 + w * 16 + l15) * HSZ + ks * 32 + l4 * 8];

  f32x4 o[4];
  float m_[4], l_[4];
#pragma unroll
  for (int i = 0; i < 4; ++i) { o[i] = (f32x4)0.f; m_[i] = -1e30f; l_[i] = 0.f; }

  LOADT(t0);
  WRITET(0);
  __syncthreads();
  int cur = 0;

  for (int kt = t0; kt < t1; ++kt) {
    const int kv0 = kt * 64;
    const bool more = (kt + 1 < t1);
    if (more) LOADT(kt + 1);

    const short* Kc = Ks[cur];
    const short* Vc = Vs[cur];

    f32x4 sacc[4];
#pragma unroll
    for (int nb = 0; nb < 4; ++nb) sacc[nb] = (f32x4)0.f;
#pragma unroll
    for (int nb = 0; nb < 4; ++nb) {
      const int krow = nb * 16 + l15;
#pragma unroll
      for (int ks = 0; ks < 2; ++ks) {
        short8 kf = *(const short8*)&Kc[krow * 64 + (((ks * 4 + l4) ^ (krow & 7)) * 8)];
        sacc[nb] = __builtin_amdgcn_mfma_f32_16x16x32_bf16(qf[ks], kf, sacc[nb],
                                                           0, 0, 0);
      }
    }

    const bool diag = (kt == qt);
#pragma unroll
    for (int reg = 0; reg < 4; ++reg) {
      const int grow = q0 + w * 16 + l4 * 4 + reg;
      float sv[4];
      float rmax = -1e30f;
#pragma unroll
      for (int nb = 0; nb < 4; ++nb) {
        sv[nb] = sacc[nb][reg] * 0.125f;
        if (diag && (kv0 + nb * 16 + l15 > grow)) sv[nb] = -1e30f;
        rmax = fmaxf(rmax, sv[nb]);
      }
#pragma unroll
      for (int d = 1; d < 16; d <<= 1) rmax = fmaxf(rmax, __shfl_xor(rmax, d));
      const float mn = fmaxf(m_[reg], rmax);
      const float sc = __expf(m_[reg] - mn);
      float rsum = 0.f;
#pragma unroll
      for (int nb = 0; nb < 4; ++nb) {
        sv[nb] = __expf(sv[nb] - mn);
        rsum += sv[nb];
      }
#pragma unroll
      for (int d = 1; d < 16; d <<= 1) rsum += __shfl_xor(rsum, d);
      l_[reg] = l_[reg] * sc + rsum;
      m_[reg] = mn;
#pragma unroll
      for (int hb = 0; hb < 4; ++hb) o[hb][reg] *= sc;
      const int prow = l4 * 4 + reg;
#pragma unroll
      for (int nb = 0; nb < 4; ++nb) {
        const int col = nb * 16 + l15;
        Ps[w][prow * 64 + (((col >> 3) ^ (prow & 7)) * 8) + (col & 7)] =
            f2bf(sv[nb]);
      }
    }

#pragma unroll
    for (int ks = 0; ks < 2; ++ks) {
      const int prow = l15;
      short8 pf = *(short8*)&Ps[w][prow * 64 + (((ks * 4 + l4) ^ (prow & 7)) * 8)];
#pragma unroll
      for (int hb = 0; hb < 4; ++hb) {
        const int vrow = hb * 16 + l15;
        short8 vf = *(const short8*)&Vc[vrow * 64 + (((ks * 4 + l4) ^ (vrow & 7)) * 8)];
        o[hb] = __builtin_amdgcn_mfma_f32_16x16x32_bf16(pf, vf, o[hb], 0, 0, 0);
      }
    }

    if (more) {
      WRITET(cur ^ 1);
      __syncthreads();
      cur ^= 1;
    }
  }
#undef LOADT
#undef WRITET

#pragma unroll
  for (int hb = 0; hb < 4; ++hb)
#pragma unroll
    for (int reg = 0; reg < 4; ++reg)
      Op[(size_t)(w * 16 + l4 * 4 + reg) * HSZ + hb * 16 + l15] = o[hb][reg];
  if (l15 == 0) {
#pragma unroll
    for (int reg = 0; reg < 4; ++reg) {
      mp[w * 16 + l4 * 4 + reg] = m_[reg];
      lp[w * 16 + l4 * 4 + reg] = l_[reg];
    }
  }
}

// ---------------------------------------------------------------------------
// Kernel 4: combine partials -> head, emitted bf16 (A-frag-ready for proj).
// ---------------------------------------------------------------------------
__global__ __launch_bounds__(256) void attn_combine(
    const float* __restrict__ Opart, const float* __restrict__ mpart,
    const float* __restrict__ lpart, short* __restrict__ Hd16, int splits) {
  const int qt = blockIdx.x, b = blockIdx.y;
  const int row = threadIdx.x >> 2;
  const int c0 = (threadIdx.x & 3) * 16;
  const int pbase = (b * NQT + qt) * splits;

  float M = -1e30f;
  for (int s = 0; s < splits; ++s)
    M = fmaxf(M, mpart[(size_t)(pbase + s) * QB + row]);

  float L = 0.f;
  float acc[16];
#pragma unroll
  for (int c = 0; c < 16; ++c) acc[c] = 0.f;

  for (int s = 0; s < splits; ++s) {
    const float ms = mpart[(size_t)(pbase + s) * QB + row];
    const float ls = lpart[(size_t)(pbase + s) * QB + row];
    const float w = __expf(ms - M);
    L += w * ls;
    const float* Op = Opart + ((size_t)(pbase + s) * QB + row) * HSZ + c0;
#pragma unroll
    for (int cc = 0; cc < 16; cc += 4) {
      float4 v = *(const float4*)&Op[cc];
      acc[cc + 0] += w * v.x; acc[cc + 1] += w * v.y;
      acc[cc + 2] += w * v.z; acc[cc + 3] += w * v.w;
    }
  }

  const float inv = 1.f / L;
  short* dst = Hd16 + ((size_t)b * T_SEQ + qt * QB + row) * HSZ + c0;
  short8 v0, v1;
#pragma unroll
  for (int cc = 0; cc < 8; ++cc) {
    v0[cc] = f2bf(acc[cc] * inv);
    v1[cc] = f2bf(acc[8 + cc] * inv);
  }
  *(short8*)dst = v0;
  *(short8*)(dst + 8) = v1;
}

// ---------------------------------------------------------------------------
// Kernel 5: Out = Head @ Wpr + bp via bf16 MFMA, ZERO LDS.
// ---------------------------------------------------------------------------
__global__ __launch_bounds__(256) void proj_mfma(const short* __restrict__ Hd16,
    const short* __restrict__ Wpb, const float* __restrict__ bp,
    float* __restrict__ Out) {
  const int tid = threadIdx.x;
  const int lane = tid & 63, w = tid >> 6;
  const int l15 = lane & 15, l4 = lane >> 4;
  const int m0 = blockIdx.x * 64 + w * 16;
  const int n0 = blockIdx.y * 128;

  const short* asrc = &Hd16[(size_t)(m0 + l15) * HSZ + l4 * 8];
  short8 af0 = *(const short8*)asrc;
  short8 af1 = *(const short8*)(asrc + 32);

#pragma unroll
  for (int nb = 0; nb < 8; ++nb) {
    const int n = n0 + nb * 16 + l15;
    const short* bsrc = &Wpb[(size_t)n * HSZ + l4 * 8];
    short8 b0 = *(const short8*)bsrc;
    short8 b1 = *(const short8*)(bsrc + 32);
    f32x4 acc = (f32x4)0.f;
    acc = __builtin_amdgcn_mfma_f32_16x16x32_bf16(af0, b0, acc, 0, 0, 0);
    acc = __builtin_amdgcn_mfma_f32_16x16x32_bf16(af1, b1, acc, 0, 0, 0);
    const float bpv = bp[n];
#pragma unroll
    for (int reg = 0; reg < 4; ++reg)
      Out[(size_t)(m0 + l4 * 4 + reg) * E_DIM + n] = acc[reg] + bpv;
  }
}

// ---------------------------------------------------------------------------
extern "C" void kernel_launch(void* const* d_in, const int* in_sizes, int n_in,
                              void* d_out, int out_size, void* d_ws,
                              size_t ws_size, hipStream_t stream) {
  (void)in_sizes; (void)n_in; (void)out_size;
  const float* x  = (const float*)d_in[0];
  const float* Wq = (const float*)d_in[1];
  const float* Wk = (const float*)d_in[2];
  const float* Wv = (const float*)d_in[3];
  const float* Wp = (const float*)d_in[4];
  const float* bp = (const float*)d_in[5];
  float* out = (float*)d_out;

  // workspace layout (float units):
  //   Qb16/Kb16/Vt16/Hd16 bf16 262144 each; Wpb bf16 32768; Wt bf16 98304.
  float* ws   = (float*)d_ws;
  short* Qb16 = (short*)(ws);
  short* Kb16 = (short*)(ws + 262144);
  short* Vt16 = (short*)(ws + 524288);
  short* Hd16 = (short*)(ws + 786432);
  short* Wpb  = (short*)(ws + 1048576);
  short* Wt   = (short*)(ws + 1081344);
  const size_t base = 1179648;

  int splits = 16;
  const size_t per_split = (size_t)NBAT * NQT * (QB * HSZ + 2 * QB);
  while (splits > 1 && (base + per_split * splits) * 4 > ws_size) splits >>= 1;

  float* Opart = ws + base;
  float* mpart = Opart + (size_t)NBAT * NQT * splits * QB * HSZ;
  float* lpart = mpart + (size_t)NBAT * NQT * splits * QB;

  prep_kernel<<<dim3(1024), dim3(256), 0, stream>>>(Wp, Wq, Wk, Wv, Wpb, Wt);
  qkv_mfma<<<dim3(256), dim3(256), 0, stream>>>(x, Wt, Qb16, Kb16, Vt16);
  attn_part<<<dim3(NQT, splits, NBAT), dim3(256), 0, stream>>>(
      Qb16, Kb16, Vt16, Opart, mpart, lpart, splits);
  attn_combine<<<dim3(NQT, NBAT), dim3(256), 0, stream>>>(
      Opart, mpart, lpart, Hd16, splits);
  proj_mfma<<<dim3(128, 8), dim3(256), 0, stream>>>(Hd16, Wpb, bp, out);
}